// Round 1
// baseline (315.528 us; speedup 1.0000x reference)
//
#include <hip/hip_runtime.h>
#include <hip/hip_bf16.h>
#include <stdint.h>

#define Ssz 1024
#define Bsz 4
#define Csz 1024
#define Hsz 16
#define Msz 4096   // S*B

typedef unsigned short u16;
typedef __attribute__((ext_vector_type(8))) short bf16x8;
typedef __attribute__((ext_vector_type(4))) float f32x4;
typedef __attribute__((ext_vector_type(4))) unsigned short u16x4;

__device__ __forceinline__ u16 f2bf(float f) {
  union { float f; unsigned u; } x; x.f = f;
  unsigned r = x.u + 0x7fffu + ((x.u >> 16) & 1u);   // RNE
  return (u16)(r >> 16);
}

__device__ __forceinline__ void glds16(const void* g, void* l) {
  __builtin_amdgcn_global_load_lds(
      (__attribute__((address_space(1))) void*)g,
      (__attribute__((address_space(3))) void*)l, 16, 0, 0);
}

// ---------------- prep 1: uwke = Wke@u + bke ; vwke = Wkr@v + bkr ----------------
__global__ __launch_bounds__(256) void k_prep1(
    const float* __restrict__ Wke, const float* __restrict__ bke, const float* __restrict__ uu,
    const float* __restrict__ Wkr, const float* __restrict__ bkr, const float* __restrict__ vv,
    float* __restrict__ uwke, float* __restrict__ vwke) {
  int w = blockIdx.x * 4 + (threadIdx.x >> 6);   // 0..2047
  int lane = threadIdx.x & 63;
  const float* Wrow; const float* vec; const float* bias; float* outp; int c;
  if (w < 1024) { c = w;        Wrow = Wke + (size_t)c * Csz; vec = uu; bias = bke; outp = uwke; }
  else          { c = w - 1024; Wrow = Wkr + (size_t)c * Csz; vec = vv; bias = bkr; outp = vwke; }
  float s = 0.f;
  const float4* W4 = (const float4*)Wrow;
  const float4* V4 = (const float4*)vec;
  #pragma unroll
  for (int i = lane; i < 256; i += 64) {
    float4 a = W4[i], b = V4[i];
    s += a.x * b.x + a.y * b.y + a.z * b.z + a.w * b.w;
  }
  for (int m = 32; m; m >>= 1) s += __shfl_xor(s, m);
  if (lane == 0) outp[c] = s + bias[c];
}

// ---------------- prep 2: wu = Wke^T uwke ; wv = Wkr^T vwke ; cst ----------------
__global__ __launch_bounds__(256) void k_prep2(
    const float* __restrict__ Wke, const float* __restrict__ Wkr,
    const float* __restrict__ uwke, const float* __restrict__ vwke,
    const float* __restrict__ bke, const float* __restrict__ bkr,
    float* __restrict__ wu, float* __restrict__ wv, float* __restrict__ cst) {
  int bid = blockIdx.x;
  if (bid < 8) {
    const float* W = (bid < 4) ? Wke : Wkr;
    const float* sv = (bid < 4) ? uwke : vwke;
    float* o = (bid < 4) ? wu : wv;
    int d = (bid & 3) * 256 + threadIdx.x;
    float acc = 0.f;
    #pragma unroll 8
    for (int c = 0; c < Csz; c++) acc += sv[c] * W[(size_t)c * Csz + d];
    o[d] = acc;
  } else {
    int t = threadIdx.x;
    float s = 0.f;
    for (int i = t; i < Csz; i += 256) s += uwke[i] * bke[i] + vwke[i] * bkr[i];
    for (int m = 32; m; m >>= 1) s += __shfl_xor(s, m);
    __shared__ float red[4];
    if ((t & 63) == 0) red[t >> 6] = s;
    __syncthreads();
    if (t == 0) cst[0] = red[0] + red[1] + red[2] + red[3];
  }
}

// ---------------- convert x,r -> A2 bf16 [4096][2048] ----------------
__global__ __launch_bounds__(256) void k_convert_xr(
    const float* __restrict__ x, const float* __restrict__ r, u16* __restrict__ A2) {
  int g = blockIdx.x * 256 + threadIdx.x;   // 0..1M-1
  int m = g >> 8;
  int c4 = (g & 255) * 4;
  float4 xv = *(const float4*)(x + (size_t)m * Csz + c4);
  float4 rv = *(const float4*)(r + (size_t)m * Csz + c4);
  u16x4 xo = { f2bf(xv.x), f2bf(xv.y), f2bf(xv.z), f2bf(xv.w) };
  u16x4 ro = { f2bf(rv.x), f2bf(rv.y), f2bf(rv.z), f2bf(rv.w) };
  *(u16x4*)(A2 + (size_t)m * 2048 + c4) = xo;
  *(u16x4*)(A2 + (size_t)m * 2048 + 1024 + c4) = ro;
}

// ---------------- convert weights -> Bq [1024][1024], B2 [1024][2048]; biasK ----------------
__global__ __launch_bounds__(256) void k_convert_w(
    const float* __restrict__ Wq, const float* __restrict__ Wke, const float* __restrict__ Wkr,
    const float* __restrict__ bke, const float* __restrict__ bkr,
    u16* __restrict__ Bq, u16* __restrict__ B2, float* __restrict__ biasK) {
  int g = blockIdx.x * 256 + threadIdx.x;
  int c = g >> 8;
  int c4 = (g & 255) * 4;
  float4 q = *(const float4*)(Wq + (size_t)c * Csz + c4);
  float4 e = *(const float4*)(Wke + (size_t)c * Csz + c4);
  float4 k = *(const float4*)(Wkr + (size_t)c * Csz + c4);
  u16x4 qo = { f2bf(q.x), f2bf(q.y), f2bf(q.z), f2bf(q.w) };
  u16x4 eo = { f2bf(e.x), f2bf(e.y), f2bf(e.z), f2bf(e.w) };
  u16x4 ko = { f2bf(k.x), f2bf(k.y), f2bf(k.z), f2bf(k.w) };
  *(u16x4*)(Bq + (size_t)c * 1024 + c4) = qo;
  *(u16x4*)(B2 + (size_t)c * 2048 + c4) = eo;
  *(u16x4*)(B2 + (size_t)c * 2048 + 1024 + c4) = ko;
  if (threadIdx.x == 0) biasK[c] = bke[c] + bkr[c];
}

// ---------------- fused projection GEMMs (z=0: Q, z=1: K) ----------------
// C[m][n] = sum_k A[m][k] * B[n][k] + bias[n]   (bf16 in/out, f32 acc)
__global__ __launch_bounds__(256) void k_gemm(
    const u16* __restrict__ A2, const u16* __restrict__ Bq, const u16* __restrict__ B2,
    const float* __restrict__ bq, const float* __restrict__ biasK,
    u16* __restrict__ Qb, u16* __restrict__ Kb) {
  __shared__ u16 As[128 * 32];
  __shared__ u16 Bs[128 * 32];
  const int z = blockIdx.z;
  const u16* A = A2; const int lda = 2048;
  const u16* B = (z == 0) ? Bq : B2;
  const int ldb = (z == 0) ? 1024 : 2048;
  const float* bias = (z == 0) ? bq : biasK;
  u16* C = (z == 0) ? Qb : Kb;
  const int K = (z == 0) ? 1024 : 2048;

  const int tid = threadIdx.x;
  const int bm = blockIdx.y * 128, bn = blockIdx.x * 128;
  const int wave = tid >> 6, lane = tid & 63;
  const int wm = (wave & 1) * 64, wn = (wave >> 1) * 64;
  const int fr = lane & 15, kg = (lane >> 4) * 8;

  f32x4 acc[4][4] = {};

  for (int kt = 0; kt < K; kt += 32) {
    __syncthreads();
    #pragma unroll
    for (int i = 0; i < 2; i++) {
      int ch = i * 256 + tid;            // 0..511, 16B chunks
      int row = ch >> 2, col = (ch & 3) * 8;
      glds16(A + (size_t)(bm + row) * lda + kt + col, As + ch * 8);
      glds16(B + (size_t)(bn + row) * ldb + kt + col, Bs + ch * 8);
    }
    __syncthreads();
    bf16x8 af[4], bf[4];
    #pragma unroll
    for (int mi = 0; mi < 4; mi++) af[mi] = *(const bf16x8*)(As + (wm + mi * 16 + fr) * 32 + kg);
    #pragma unroll
    for (int ni = 0; ni < 4; ni++) bf[ni] = *(const bf16x8*)(Bs + (wn + ni * 16 + fr) * 32 + kg);
    #pragma unroll
    for (int mi = 0; mi < 4; mi++)
      #pragma unroll
      for (int ni = 0; ni < 4; ni++)
        acc[mi][ni] = __builtin_amdgcn_mfma_f32_16x16x32_bf16(af[mi], bf[ni], acc[mi][ni], 0, 0, 0);
  }

  const int rg = (lane >> 4) * 4;
  #pragma unroll
  for (int ni = 0; ni < 4; ni++) {
    int col = bn + wn + ni * 16 + fr;
    float bv = bias[col];
    #pragma unroll
    for (int mi = 0; mi < 4; mi++) {
      #pragma unroll
      for (int j = 0; j < 4; j++) {
        int row = bm + wm + mi * 16 + rg + j;
        C[(size_t)row * 1024 + col] = f2bf(acc[mi][ni][j] + bv);
      }
    }
  }
}

// ---------------- bias[t*4+b] = x[t,b]·wu + r[t,b]·wv + cst ----------------
__global__ __launch_bounds__(256) void k_bias(
    const float* __restrict__ x, const float* __restrict__ r,
    const float* __restrict__ wu, const float* __restrict__ wv,
    const float* __restrict__ cst, float* __restrict__ biasTB) {
  int row = blockIdx.x * 4 + (threadIdx.x >> 6);   // 0..4095
  int lane = threadIdx.x & 63;
  const float4* xv = (const float4*)(x + (size_t)row * Csz);
  const float4* rv = (const float4*)(r + (size_t)row * Csz);
  const float4* wuv = (const float4*)wu;
  const float4* wvv = (const float4*)wv;
  float s = 0.f;
  #pragma unroll
  for (int i = lane; i < 256; i += 64) {
    float4 a = xv[i], b = wuv[i];
    s += a.x * b.x + a.y * b.y + a.z * b.z + a.w * b.w;
    float4 c = rv[i], d = wvv[i];
    s += c.x * d.x + c.y * d.y + c.z * d.z + c.w * d.w;
  }
  for (int m = 32; m; m >>= 1) s += __shfl_xor(s, m);
  if (lane == 0) biasTB[row] = s + cst[0];
}

// ---------------- attention: out[s,t,b,n] = sum_c Q[s,b,n,c]*K[t,b,n,c] + bias[t,b] ----------------
// wg: one b, 32x32 (s,t) tile, all 16 heads. 4 waves = 2x2 quadrants of 16x16.
__global__ __launch_bounds__(256) void k_attn(
    const u16* __restrict__ Q, const u16* __restrict__ Kb,
    const float* __restrict__ biasTB, float* __restrict__ out) {
  int id = blockIdx.x;                       // 0..4095
  int idx = (id & 7) * 512 + (id >> 3);      // XCD swizzle (4096 % 8 == 0)
  int b  = idx >> 10;
  int st = (idx >> 5) & 31;
  int tt = idx & 31;
  int wave = threadIdx.x >> 6, lane = threadIdx.x & 63;
  int sh = wave & 1, th = wave >> 1;
  int fr = lane & 15, kg = (lane >> 4) * 8;
  int s_row = st * 32 + sh * 16 + fr;
  int t_row = tt * 32 + th * 16 + fr;
  const u16* qp = Q  + (size_t)(s_row * 4 + b) * 1024 + kg;
  const u16* kp = Kb + (size_t)(t_row * 4 + b) * 1024 + kg;

  f32x4 acc[16];
  #pragma unroll
  for (int n = 0; n < 16; n++) acc[n] = (f32x4){0.f, 0.f, 0.f, 0.f};

  #pragma unroll
  for (int n = 0; n < 16; n++) {
    #pragma unroll
    for (int kk = 0; kk < 2; kk++) {
      bf16x8 a  = *(const bf16x8*)(qp + n * 64 + kk * 32);
      bf16x8 bb = *(const bf16x8*)(kp + n * 64 + kk * 32);
      acc[n] = __builtin_amdgcn_mfma_f32_16x16x32_bf16(a, bb, acc[n], 0, 0, 0);
    }
  }

  float bv = biasTB[t_row * 4 + b];          // D col for this lane is t_row
  int rg = (lane >> 4) * 4;
  #pragma unroll
  for (int j = 0; j < 4; j++) {
    int s = st * 32 + sh * 16 + rg + j;
    float* op = out + ((size_t)(s * 1024 + t_row) * 4 + b) * 16;
    #pragma unroll
    for (int a4 = 0; a4 < 4; a4++) {
      float4 vst = { acc[a4 * 4 + 0][j] + bv, acc[a4 * 4 + 1][j] + bv,
                     acc[a4 * 4 + 2][j] + bv, acc[a4 * 4 + 3][j] + bv };
      *(float4*)(op + a4 * 4) = vst;
    }
  }
}

extern "C" void kernel_launch(void* const* d_in, const int* in_sizes, int n_in,
                              void* d_out, int out_size, void* d_ws, size_t ws_size,
                              hipStream_t stream) {
  const float* x   = (const float*)d_in[0];
  const float* r   = (const float*)d_in[1];
  const float* Wq  = (const float*)d_in[2];
  const float* bq  = (const float*)d_in[3];
  const float* Wke = (const float*)d_in[4];
  const float* bke = (const float*)d_in[5];
  const float* Wkr = (const float*)d_in[6];
  const float* bkr = (const float*)d_in[7];
  const float* uu  = (const float*)d_in[8];
  const float* vv  = (const float*)d_in[9];
  float* out = (float*)d_out;
  char* ws = (char*)d_ws;

  u16* A2 = (u16*)(ws + 0);                  // 16 MB  [4096][2048] bf16
  u16* Qb = (u16*)(ws + 16777216);           // 8 MB   [4096][1024]
  u16* Kb = (u16*)(ws + 25165824);           // 8 MB   [4096][1024]
  u16* B2 = (u16*)(ws + 33554432);           // 4 MB   [1024][2048]
  u16* Bq = (u16*)(ws + 37748736);           // 2 MB   [1024][1024]
  float* uwke  = (float*)(ws + 39845888);
  float* vwke  = (float*)(ws + 39849984);
  float* wu    = (float*)(ws + 39854080);
  float* wv    = (float*)(ws + 39858176);
  float* biasK = (float*)(ws + 39862272);
  float* cst   = (float*)(ws + 39866368);
  float* biasTB = (float*)(ws + 39866624);   // 16 KB [1024*4]

  k_prep1<<<512, 256, 0, stream>>>(Wke, bke, uu, Wkr, bkr, vv, uwke, vwke);
  k_prep2<<<9, 256, 0, stream>>>(Wke, Wkr, uwke, vwke, bke, bkr, wu, wv, cst);
  k_convert_xr<<<4096, 256, 0, stream>>>(x, r, A2);
  k_convert_w<<<1024, 256, 0, stream>>>(Wq, Wke, Wkr, bke, bkr, Bq, B2, biasK);
  k_gemm<<<dim3(8, 32, 2), 256, 0, stream>>>(A2, Bq, B2, bq, biasK, Qb, Kb);
  k_bias<<<1024, 256, 0, stream>>>(x, r, wu, wv, cst, biasTB);
  k_attn<<<4096, 256, 0, stream>>>(Qb, Kb, biasTB, out);
}

// Round 2
// 216.765 us; speedup vs baseline: 1.4556x; 1.4556x over previous
//
#include <hip/hip_runtime.h>
#include <hip/hip_bf16.h>
#include <stdint.h>

#define Ssz 1024
#define Bsz 4
#define Csz 1024
#define Hsz 16
#define Msz 4096   // S*B

typedef unsigned short u16;
typedef __attribute__((ext_vector_type(8))) short bf16x8;
typedef __attribute__((ext_vector_type(4))) float f32x4;
typedef __attribute__((ext_vector_type(4))) unsigned short u16x4;

__device__ __forceinline__ u16 f2bf(float f) {
  union { float f; unsigned u; } x; x.f = f;
  unsigned r = x.u + 0x7fffu + ((x.u >> 16) & 1u);   // RNE
  return (u16)(r >> 16);
}

__device__ __forceinline__ void glds16(const void* g, void* l) {
  __builtin_amdgcn_global_load_lds(
      (__attribute__((address_space(1))) void*)g,
      (__attribute__((address_space(3))) void*)l, 16, 0, 0);
}

// XOR-swizzle a logical LDS byte offset (bank-spread for 256B-strided rows)
__device__ __forceinline__ int swzb(int x) { return x ^ (((x >> 8) & 7) << 4); }

// ---------------- prep 1: uwke = Wke@u + bke ; vwke = Wkr@v + bkr ----------------
__global__ __launch_bounds__(256) void k_prep1(
    const float* __restrict__ Wke, const float* __restrict__ bke, const float* __restrict__ uu,
    const float* __restrict__ Wkr, const float* __restrict__ bkr, const float* __restrict__ vv,
    float* __restrict__ uwke, float* __restrict__ vwke) {
  int w = blockIdx.x * 4 + (threadIdx.x >> 6);   // 0..2047
  int lane = threadIdx.x & 63;
  const float* Wrow; const float* vec; const float* bias; float* outp; int c;
  if (w < 1024) { c = w;        Wrow = Wke + (size_t)c * Csz; vec = uu; bias = bke; outp = uwke; }
  else          { c = w - 1024; Wrow = Wkr + (size_t)c * Csz; vec = vv; bias = bkr; outp = vwke; }
  float s = 0.f;
  const float4* W4 = (const float4*)Wrow;
  const float4* V4 = (const float4*)vec;
  #pragma unroll
  for (int i = lane; i < 256; i += 64) {
    float4 a = W4[i], b = V4[i];
    s += a.x * b.x + a.y * b.y + a.z * b.z + a.w * b.w;
  }
  for (int m = 32; m; m >>= 1) s += __shfl_xor(s, m);
  if (lane == 0) outp[c] = s + bias[c];
}

// ---------------- prep 2: wu = Wke^T uwke ; wv = Wkr^T vwke ; cst ----------------
// grid 65: bid<64 -> (mat = bid>>5, d-chunk = bid&31); bid==64 -> cst
__global__ __launch_bounds__(256) void k_prep2(
    const float* __restrict__ Wke, const float* __restrict__ Wkr,
    const float* __restrict__ uwke, const float* __restrict__ vwke,
    const float* __restrict__ bke, const float* __restrict__ bkr,
    float* __restrict__ wu, float* __restrict__ wv, float* __restrict__ cst) {
  int bid = blockIdx.x;
  int tid = threadIdx.x;
  if (bid < 64) {
    const float* W = (bid < 32) ? Wke : Wkr;
    const float* sv = (bid < 32) ? uwke : vwke;
    float* o = (bid < 32) ? wu : wv;
    int d = (bid & 31) * 32 + (tid & 31);
    int cpar = tid >> 5;                    // 0..7
    float acc = 0.f;
    #pragma unroll 8
    for (int c = cpar; c < Csz; c += 8) acc += sv[c] * W[(size_t)c * Csz + d];
    __shared__ float red[8][32];
    red[cpar][tid & 31] = acc;
    __syncthreads();
    if (cpar == 0) {
      float s = 0.f;
      #pragma unroll
      for (int i = 0; i < 8; i++) s += red[i][tid & 31];
      o[d] = s;
    }
  } else {
    float s = 0.f;
    for (int i = tid; i < Csz; i += 256) s += uwke[i] * bke[i] + vwke[i] * bkr[i];
    for (int m = 32; m; m >>= 1) s += __shfl_xor(s, m);
    __shared__ float red1[4];
    if ((tid & 63) == 0) red1[tid >> 6] = s;
    __syncthreads();
    if (tid == 0) cst[0] = red1[0] + red1[1] + red1[2] + red1[3];
  }
}

// ---------------- convert x,r -> A2 bf16 [4096][2048] ----------------
__global__ __launch_bounds__(256) void k_convert_xr(
    const float* __restrict__ x, const float* __restrict__ r, u16* __restrict__ A2) {
  int g = blockIdx.x * 256 + threadIdx.x;   // 0..1M-1
  int m = g >> 8;
  int c4 = (g & 255) * 4;
  float4 xv = *(const float4*)(x + (size_t)m * Csz + c4);
  float4 rv = *(const float4*)(r + (size_t)m * Csz + c4);
  u16x4 xo = { f2bf(xv.x), f2bf(xv.y), f2bf(xv.z), f2bf(xv.w) };
  u16x4 ro = { f2bf(rv.x), f2bf(rv.y), f2bf(rv.z), f2bf(rv.w) };
  *(u16x4*)(A2 + (size_t)m * 2048 + c4) = xo;
  *(u16x4*)(A2 + (size_t)m * 2048 + 1024 + c4) = ro;
}

// ---------------- convert weights -> Bq [1024][1024], B2 [1024][2048]; biasK ----------------
__global__ __launch_bounds__(256) void k_convert_w(
    const float* __restrict__ Wq, const float* __restrict__ Wke, const float* __restrict__ Wkr,
    const float* __restrict__ bke, const float* __restrict__ bkr,
    u16* __restrict__ Bq, u16* __restrict__ B2, float* __restrict__ biasK) {
  int g = blockIdx.x * 256 + threadIdx.x;
  int c = g >> 8;
  int c4 = (g & 255) * 4;
  float4 q = *(const float4*)(Wq + (size_t)c * Csz + c4);
  float4 e = *(const float4*)(Wke + (size_t)c * Csz + c4);
  float4 k = *(const float4*)(Wkr + (size_t)c * Csz + c4);
  u16x4 qo = { f2bf(q.x), f2bf(q.y), f2bf(q.z), f2bf(q.w) };
  u16x4 eo = { f2bf(e.x), f2bf(e.y), f2bf(e.z), f2bf(e.w) };
  u16x4 ko = { f2bf(k.x), f2bf(k.y), f2bf(k.z), f2bf(k.w) };
  *(u16x4*)(Bq + (size_t)c * 1024 + c4) = qo;
  *(u16x4*)(B2 + (size_t)c * 2048 + c4) = eo;
  *(u16x4*)(B2 + (size_t)c * 2048 + 1024 + c4) = ko;
  if (threadIdx.x == 0) biasK[c] = bke[c] + bkr[c];
}

// ---------------- fused projection GEMMs (z=0: Q, z=1: K) ----------------
__global__ __launch_bounds__(256) void k_gemm(
    const u16* __restrict__ A2, const u16* __restrict__ Bq, const u16* __restrict__ B2,
    const float* __restrict__ bq, const float* __restrict__ biasK,
    u16* __restrict__ Qb, u16* __restrict__ Kb) {
  __shared__ u16 As[128 * 32];
  __shared__ u16 Bs[128 * 32];
  const int z = blockIdx.z;
  const u16* A = A2; const int lda = 2048;
  const u16* B = (z == 0) ? Bq : B2;
  const int ldb = (z == 0) ? 1024 : 2048;
  const float* bias = (z == 0) ? bq : biasK;
  u16* C = (z == 0) ? Qb : Kb;
  const int K = (z == 0) ? 1024 : 2048;

  const int tid = threadIdx.x;
  const int bm = blockIdx.y * 128, bn = blockIdx.x * 128;
  const int wave = tid >> 6, lane = tid & 63;
  const int wm = (wave & 1) * 64, wn = (wave >> 1) * 64;
  const int fr = lane & 15, kg = (lane >> 4) * 8;

  f32x4 acc[4][4] = {};

  for (int kt = 0; kt < K; kt += 32) {
    __syncthreads();
    #pragma unroll
    for (int i = 0; i < 2; i++) {
      int ch = i * 256 + tid;            // 0..511, 16B chunks
      int row = ch >> 2, col = (ch & 3) * 8;
      glds16(A + (size_t)(bm + row) * lda + kt + col, As + ch * 8);
      glds16(B + (size_t)(bn + row) * ldb + kt + col, Bs + ch * 8);
    }
    __syncthreads();
    bf16x8 af[4], bf[4];
    #pragma unroll
    for (int mi = 0; mi < 4; mi++) af[mi] = *(const bf16x8*)(As + (wm + mi * 16 + fr) * 32 + kg);
    #pragma unroll
    for (int ni = 0; ni < 4; ni++) bf[ni] = *(const bf16x8*)(Bs + (wn + ni * 16 + fr) * 32 + kg);
    #pragma unroll
    for (int mi = 0; mi < 4; mi++)
      #pragma unroll
      for (int ni = 0; ni < 4; ni++)
        acc[mi][ni] = __builtin_amdgcn_mfma_f32_16x16x32_bf16(af[mi], bf[ni], acc[mi][ni], 0, 0, 0);
  }

  const int rg = (lane >> 4) * 4;
  #pragma unroll
  for (int ni = 0; ni < 4; ni++) {
    int col = bn + wn + ni * 16 + fr;
    float bv = bias[col];
    #pragma unroll
    for (int mi = 0; mi < 4; mi++) {
      #pragma unroll
      for (int j = 0; j < 4; j++) {
        int row = bm + wm + mi * 16 + rg + j;
        C[(size_t)row * 1024 + col] = f2bf(acc[mi][ni][j] + bv);
      }
    }
  }
}

// ---------------- bias[t*4+b] = x[t,b]·wu + r[t,b]·wv + cst ----------------
__global__ __launch_bounds__(256) void k_bias(
    const float* __restrict__ x, const float* __restrict__ r,
    const float* __restrict__ wu, const float* __restrict__ wv,
    const float* __restrict__ cst, float* __restrict__ biasTB) {
  int row = blockIdx.x * 4 + (threadIdx.x >> 6);   // 0..4095
  int lane = threadIdx.x & 63;
  const float4* xv = (const float4*)(x + (size_t)row * Csz);
  const float4* rv = (const float4*)(r + (size_t)row * Csz);
  const float4* wuv = (const float4*)wu;
  const float4* wvv = (const float4*)wv;
  float s = 0.f;
  #pragma unroll
  for (int i = lane; i < 256; i += 64) {
    float4 a = xv[i], b = wuv[i];
    s += a.x * b.x + a.y * b.y + a.z * b.z + a.w * b.w;
    float4 c = rv[i], d = wvv[i];
    s += c.x * d.x + c.y * d.y + c.z * d.z + c.w * d.w;
  }
  for (int m = 32; m; m >>= 1) s += __shfl_xor(s, m);
  if (lane == 0) biasTB[row] = s + cst[0];
}

// ---------------- attention ----------------
// out[s,t,b,n] = sum_c Q[s,b,n,c]*K[t,b,n,c] + bias[t,b]
// Block: 16x16 (s,t) tile x all 4 b (wave=b) x all 16 heads.
// Results staged through 32KB swizzled LDS, stored as 4KB contiguous rows.
__global__ __launch_bounds__(256, 3) void k_attn(
    const u16* __restrict__ Q, const u16* __restrict__ Kb,
    const float* __restrict__ biasTB, float* __restrict__ out) {
  // XCD-aware 2D partition: xcd -> (sx, tx); t-panels of 8 tiles for L2 residency
  int id = blockIdx.x;                  // 0..4095
  int xcd = id & 7, within = id >> 3;   // dispatch round-robins ids across XCDs
  int sx = xcd & 3, tx = xcd >> 2;
  int panel = within >> 7;              // 0..3
  int pl = within & 127;
  int s_tile = sx * 16 + (pl >> 3);     // 0..63
  int t_tile = tx * 32 + panel * 8 + (pl & 7);
  int s0 = s_tile * 16, t0 = t_tile * 16;

  int tid = threadIdx.x;
  int wave = tid >> 6, lane = tid & 63; // wave = b
  int fr = lane & 15, kg8 = (lane >> 4) * 8;

  const u16* qp = Q  + (size_t)((s0 + fr) * 4 + wave) * 1024 + kg8;
  const u16* kp = Kb + (size_t)((t0 + fr) * 4 + wave) * 1024 + kg8;

  f32x4 acc[16];
  #pragma unroll
  for (int n = 0; n < 16; n++) acc[n] = (f32x4){0.f, 0.f, 0.f, 0.f};

  #pragma unroll
  for (int n = 0; n < 16; n++) {
    #pragma unroll
    for (int kk = 0; kk < 2; kk++) {
      bf16x8 a  = *(const bf16x8*)(qp + n * 64 + kk * 32);
      bf16x8 bb = *(const bf16x8*)(kp + n * 64 + kk * 32);
      acc[n] = __builtin_amdgcn_mfma_f32_16x16x32_bf16(a, bb, acc[n], 0, 0, 0);
    }
  }

  // stage + store: 2 phases of 8 s-rows through LDS [8][16][4][16] f32 (32KB)
  __shared__ float lds[8192];
  float bv = biasTB[(t0 + (tid >> 4)) * 4 + ((tid >> 2) & 3)];
  int hi = (lane >> 4) & 1;
  int myg = (lane >> 4) >> 1;           // this lane's acc rows live in phase myg

  #pragma unroll
  for (int g = 0; g < 2; g++) {
    __syncthreads();
    if (myg == g) {
      #pragma unroll
      for (int j = 0; j < 4; j++) {
        int lbase = (((hi * 4 + j) * 16 + fr) * 4 + wave) * 64;   // logical byte
        #pragma unroll
        for (int n0 = 0; n0 < 16; n0 += 4) {
          f32x4 v = { acc[n0][j], acc[n0 + 1][j], acc[n0 + 2][j], acc[n0 + 3][j] };
          *(f32x4*)((char*)lds + swzb(lbase + n0 * 4)) = v;
        }
      }
    }
    __syncthreads();
    #pragma unroll
    for (int sr = 0; sr < 8; sr++) {
      f32x4 v = *(const f32x4*)((char*)lds + swzb(sr * 4096 + tid * 16));
      v += bv;
      size_t off = ((size_t)(s0 + g * 8 + sr) * 1024 + t0) * 64 + tid * 4;
      __builtin_nontemporal_store(v, (f32x4*)(out + off));
    }
  }
}

extern "C" void kernel_launch(void* const* d_in, const int* in_sizes, int n_in,
                              void* d_out, int out_size, void* d_ws, size_t ws_size,
                              hipStream_t stream) {
  const float* x   = (const float*)d_in[0];
  const float* r   = (const float*)d_in[1];
  const float* Wq  = (const float*)d_in[2];
  const float* bq  = (const float*)d_in[3];
  const float* Wke = (const float*)d_in[4];
  const float* bke = (const float*)d_in[5];
  const float* Wkr = (const float*)d_in[6];
  const float* bkr = (const float*)d_in[7];
  const float* uu  = (const float*)d_in[8];
  const float* vv  = (const float*)d_in[9];
  float* out = (float*)d_out;
  char* ws = (char*)d_ws;

  u16* A2 = (u16*)(ws + 0);                  // 16 MB  [4096][2048] bf16
  u16* Qb = (u16*)(ws + 16777216);           // 8 MB   [4096][1024]
  u16* Kb = (u16*)(ws + 25165824);           // 8 MB   [4096][1024]
  u16* B2 = (u16*)(ws + 33554432);           // 4 MB   [1024][2048]
  u16* Bq = (u16*)(ws + 37748736);           // 2 MB   [1024][1024]
  float* uwke  = (float*)(ws + 39845888);
  float* vwke  = (float*)(ws + 39849984);
  float* wu    = (float*)(ws + 39854080);
  float* wv    = (float*)(ws + 39858176);
  float* biasK = (float*)(ws + 39862272);
  float* cst   = (float*)(ws + 39866368);
  float* biasTB = (float*)(ws + 39866624);   // 16 KB [1024*4]

  k_prep1<<<512, 256, 0, stream>>>(Wke, bke, uu, Wkr, bkr, vv, uwke, vwke);
  k_prep2<<<65, 256, 0, stream>>>(Wke, Wkr, uwke, vwke, bke, bkr, wu, wv, cst);
  k_convert_xr<<<4096, 256, 0, stream>>>(x, r, A2);
  k_convert_w<<<1024, 256, 0, stream>>>(Wq, Wke, Wkr, bke, bkr, Bq, B2, biasK);
  k_gemm<<<dim3(8, 32, 2), 256, 0, stream>>>(A2, Bq, B2, bq, biasK, Qb, Kb);
  k_bias<<<1024, 256, 0, stream>>>(x, r, wu, wv, cst, biasTB);
  k_attn<<<4096, 256, 0, stream>>>(Qb, Kb, biasTB, out);
}

// Round 3
// 150.819 us; speedup vs baseline: 2.0921x; 1.4373x over previous
//
#include <hip/hip_runtime.h>
#include <hip/hip_bf16.h>
#include <stdint.h>

#define Ssz 1024
#define Bsz 4
#define Csz 1024
#define Hsz 16
#define Msz 4096   // S*B

typedef unsigned short u16;
typedef __attribute__((ext_vector_type(8))) short bf16x8;
typedef __attribute__((ext_vector_type(8))) unsigned short u16x8;
typedef __attribute__((ext_vector_type(4))) float f32x4;
typedef __attribute__((ext_vector_type(4))) unsigned short u16x4;

__device__ __forceinline__ u16 f2bf(float f) {
  union { float f; unsigned u; } x; x.f = f;
  unsigned r = x.u + 0x7fffu + ((x.u >> 16) & 1u);   // RNE
  return (u16)(r >> 16);
}

__device__ __forceinline__ void glds16(const void* g, void* l) {
  __builtin_amdgcn_global_load_lds(
      (__attribute__((address_space(1))) void*)g,
      (__attribute__((address_space(3))) void*)l, 16, 0, 0);
}

// XOR-swizzle a logical LDS byte offset (bank-spread for 256B-strided rows)
__device__ __forceinline__ int swzb(int x) { return x ^ (((x >> 8) & 7) << 4); }

// ---------------- prep 1: uwke = Wke@u + bke ; vwke = Wkr@v + bkr ----------------
__global__ __launch_bounds__(256) void k_prep1(
    const float* __restrict__ Wke, const float* __restrict__ bke, const float* __restrict__ uu,
    const float* __restrict__ Wkr, const float* __restrict__ bkr, const float* __restrict__ vv,
    float* __restrict__ uwke, float* __restrict__ vwke) {
  int w = blockIdx.x * 4 + (threadIdx.x >> 6);   // 0..2047
  int lane = threadIdx.x & 63;
  const float* Wrow; const float* vec; const float* bias; float* outp; int c;
  if (w < 1024) { c = w;        Wrow = Wke + (size_t)c * Csz; vec = uu; bias = bke; outp = uwke; }
  else          { c = w - 1024; Wrow = Wkr + (size_t)c * Csz; vec = vv; bias = bkr; outp = vwke; }
  float s = 0.f;
  const float4* W4 = (const float4*)Wrow;
  const float4* V4 = (const float4*)vec;
  #pragma unroll
  for (int i = lane; i < 256; i += 64) {
    float4 a = W4[i], b = V4[i];
    s += a.x * b.x + a.y * b.y + a.z * b.z + a.w * b.w;
  }
  for (int m = 32; m; m >>= 1) s += __shfl_xor(s, m);
  if (lane == 0) outp[c] = s + bias[c];
}

// ---------------- prep 2: wu = Wke^T uwke ; wv = Wkr^T vwke ; cst ----------------
__global__ __launch_bounds__(256) void k_prep2(
    const float* __restrict__ Wke, const float* __restrict__ Wkr,
    const float* __restrict__ uwke, const float* __restrict__ vwke,
    const float* __restrict__ bke, const float* __restrict__ bkr,
    float* __restrict__ wu, float* __restrict__ wv, float* __restrict__ cst) {
  int bid = blockIdx.x;
  int tid = threadIdx.x;
  if (bid < 64) {
    const float* W = (bid < 32) ? Wke : Wkr;
    const float* sv = (bid < 32) ? uwke : vwke;
    float* o = (bid < 32) ? wu : wv;
    int d = (bid & 31) * 32 + (tid & 31);
    int cpar = tid >> 5;                    // 0..7
    float acc = 0.f;
    #pragma unroll 8
    for (int c = cpar; c < Csz; c += 8) acc += sv[c] * W[(size_t)c * Csz + d];
    __shared__ float red[8][32];
    red[cpar][tid & 31] = acc;
    __syncthreads();
    if (cpar == 0) {
      float s = 0.f;
      #pragma unroll
      for (int i = 0; i < 8; i++) s += red[i][tid & 31];
      o[d] = s;
    }
  } else {
    float s = 0.f;
    for (int i = tid; i < Csz; i += 256) s += uwke[i] * bke[i] + vwke[i] * bkr[i];
    for (int m = 32; m; m >>= 1) s += __shfl_xor(s, m);
    __shared__ float red1[4];
    if ((tid & 63) == 0) red1[tid >> 6] = s;
    __syncthreads();
    if (tid == 0) cst[0] = red1[0] + red1[1] + red1[2] + red1[3];
  }
}

// ---------------- convert x,r -> A2 bf16 [4096][2048] ----------------
__global__ __launch_bounds__(256) void k_convert_xr(
    const float* __restrict__ x, const float* __restrict__ r, u16* __restrict__ A2) {
  int g = blockIdx.x * 256 + threadIdx.x;   // 0..1M-1
  int m = g >> 8;
  int c4 = (g & 255) * 4;
  float4 xv = *(const float4*)(x + (size_t)m * Csz + c4);
  float4 rv = *(const float4*)(r + (size_t)m * Csz + c4);
  u16x4 xo = { f2bf(xv.x), f2bf(xv.y), f2bf(xv.z), f2bf(xv.w) };
  u16x4 ro = { f2bf(rv.x), f2bf(rv.y), f2bf(rv.z), f2bf(rv.w) };
  *(u16x4*)(A2 + (size_t)m * 2048 + c4) = xo;
  *(u16x4*)(A2 + (size_t)m * 2048 + 1024 + c4) = ro;
}

// ---------------- convert weights -> Bq [1024][1024], B2 [1024][2048]; biasK ----------------
__global__ __launch_bounds__(256) void k_convert_w(
    const float* __restrict__ Wq, const float* __restrict__ Wke, const float* __restrict__ Wkr,
    const float* __restrict__ bke, const float* __restrict__ bkr,
    u16* __restrict__ Bq, u16* __restrict__ B2, float* __restrict__ biasK) {
  int g = blockIdx.x * 256 + threadIdx.x;
  int c = g >> 8;
  int c4 = (g & 255) * 4;
  float4 q = *(const float4*)(Wq + (size_t)c * Csz + c4);
  float4 e = *(const float4*)(Wke + (size_t)c * Csz + c4);
  float4 k = *(const float4*)(Wkr + (size_t)c * Csz + c4);
  u16x4 qo = { f2bf(q.x), f2bf(q.y), f2bf(q.z), f2bf(q.w) };
  u16x4 eo = { f2bf(e.x), f2bf(e.y), f2bf(e.z), f2bf(e.w) };
  u16x4 ko = { f2bf(k.x), f2bf(k.y), f2bf(k.z), f2bf(k.w) };
  *(u16x4*)(Bq + (size_t)c * 1024 + c4) = qo;
  *(u16x4*)(B2 + (size_t)c * 2048 + c4) = eo;
  *(u16x4*)(B2 + (size_t)c * 2048 + 1024 + c4) = ko;
  if (threadIdx.x == 0) biasK[c] = bke[c] + bkr[c];
}

// ---------------- fused projection GEMMs (z=0: Q, z=1: K) ----------------
// Output in MFMA-fragment-major layout:
//   OF[((s_tile*4 + b)*16 + head)*2 + kk][lane][e]  (512 u16 = 1KB chunks)
// where the chunk holds A/B-fragment for 16 rows (s_tile) x 32 k (kk half of head).
__global__ __launch_bounds__(256) void k_gemm(
    const u16* __restrict__ A2, const u16* __restrict__ Bq, const u16* __restrict__ B2,
    const float* __restrict__ bq, const float* __restrict__ biasK,
    u16* __restrict__ QF, u16* __restrict__ KF) {
  __shared__ u16 As[128 * 32];
  __shared__ u16 Bs[128 * 32];
  __shared__ u16 ep[4][4096];          // 8KB per-wave transpose staging
  const int z = blockIdx.z;
  const u16* A = A2; const int lda = 2048;
  const u16* B = (z == 0) ? Bq : B2;
  const int ldb = (z == 0) ? 1024 : 2048;
  const float* bias = (z == 0) ? bq : biasK;
  u16* OF = (z == 0) ? QF : KF;
  const int K = (z == 0) ? 1024 : 2048;

  const int tid = threadIdx.x;
  const int bm = blockIdx.y * 128, bn = blockIdx.x * 128;
  const int wave = tid >> 6, lane = tid & 63;
  const int wm = (wave & 1) * 64, wn = (wave >> 1) * 64;
  const int fr = lane & 15, kg = (lane >> 4) * 8;

  f32x4 acc[4][4] = {};

  for (int kt = 0; kt < K; kt += 32) {
    __syncthreads();
    #pragma unroll
    for (int i = 0; i < 2; i++) {
      int ch = i * 256 + tid;            // 0..511, 16B chunks
      int row = ch >> 2, col = (ch & 3) * 8;
      glds16(A + (size_t)(bm + row) * lda + kt + col, As + ch * 8);
      glds16(B + (size_t)(bn + row) * ldb + kt + col, Bs + ch * 8);
    }
    __syncthreads();
    bf16x8 af[4], bf[4];
    #pragma unroll
    for (int mi = 0; mi < 4; mi++) af[mi] = *(const bf16x8*)(As + (wm + mi * 16 + fr) * 32 + kg);
    #pragma unroll
    for (int ni = 0; ni < 4; ni++) bf[ni] = *(const bf16x8*)(Bs + (wn + ni * 16 + fr) * 32 + kg);
    #pragma unroll
    for (int mi = 0; mi < 4; mi++)
      #pragma unroll
      for (int ni = 0; ni < 4; ni++)
        acc[mi][ni] = __builtin_amdgcn_mfma_f32_16x16x32_bf16(af[mi], bf[ni], acc[mi][ni], 0, 0, 0);
  }

  // ---- epilogue: per-wave transpose C (m=s*4+b rows, n=channel cols) into
  // fragment layout. Wave's 64x64 sub-tile = one (s_tile16, all b, one head).
  // Source: lane(fr,hi), frag(mi,ni), j: m = bm+wm+mi*16+hi*4+j  (b=j, s16 = mi*4+hi)
  //         c = bn+wn+ni*16+fr  (cin = ni*16+fr: kk=ni>>1, g=(ni*2+(fr>>3))&3, e=fr&7)
  // Target plane p=b*2+kk (512 u16): [l'=g*16+s16][e]
  const int hi = lane >> 4;
  const int e8 = fr & 7;
  const int fr3 = fr >> 3;
  float bvn[4];
  #pragma unroll
  for (int ni = 0; ni < 4; ni++) bvn[ni] = bias[bn + wn + ni * 16 + fr];
  #pragma unroll
  for (int ni = 0; ni < 4; ni++) {
    const int kk = ni >> 1;
    const int g = (ni * 2 + fr3) & 3;
    #pragma unroll
    for (int mi = 0; mi < 4; mi++) {
      const int inner = (g * 16 + mi * 4 + hi) * 8 + e8;
      #pragma unroll
      for (int j = 0; j < 4; j++)
        ep[wave][(j * 2 + kk) * 512 + inner] = f2bf(acc[mi][ni][j] + bvn[ni]);
    }
  }
  const int s_tile = (bm >> 6) + (wm >> 6);
  const int nh = (bn + wn) >> 6;
  #pragma unroll
  for (int p = 0; p < 8; p++) {
    const int b2 = p >> 1, kk = p & 1;
    u16x8 v = *(const u16x8*)(&ep[wave][p * 512 + lane * 8]);
    size_t ci = ((size_t)(s_tile * 4 + b2) * 16 + nh) * 2 + kk;
    *(u16x8*)(OF + ci * 512 + lane * 8) = v;
  }
}

// ---------------- bias[t*4+b] = x[t,b]·wu + r[t,b]·wv + cst ----------------
__global__ __launch_bounds__(256) void k_bias(
    const float* __restrict__ x, const float* __restrict__ r,
    const float* __restrict__ wu, const float* __restrict__ wv,
    const float* __restrict__ cst, float* __restrict__ biasTB) {
  int row = blockIdx.x * 4 + (threadIdx.x >> 6);   // 0..4095
  int lane = threadIdx.x & 63;
  const float4* xv = (const float4*)(x + (size_t)row * Csz);
  const float4* rv = (const float4*)(r + (size_t)row * Csz);
  const float4* wuv = (const float4*)wu;
  const float4* wvv = (const float4*)wv;
  float s = 0.f;
  #pragma unroll
  for (int i = lane; i < 256; i += 64) {
    float4 a = xv[i], b = wuv[i];
    s += a.x * b.x + a.y * b.y + a.z * b.z + a.w * b.w;
    float4 c = rv[i], d = wvv[i];
    s += c.x * d.x + c.y * d.y + c.z * d.z + c.w * d.w;
  }
  for (int m = 32; m; m >>= 1) s += __shfl_xor(s, m);
  if (lane == 0) biasTB[row] = s + cst[0];
}

// ---------------- attention ----------------
// out[s,t,b,n] = sum_c Q[s,b,n,c]*K[t,b,n,c] + bias[t,b]
// QF/KF are fragment-major: every operand load = 64 lanes x 16B contiguous.
__global__ __launch_bounds__(256, 3) void k_attn(
    const u16* __restrict__ QF, const u16* __restrict__ KF,
    const float* __restrict__ biasTB, float* __restrict__ out) {
  // XCD-aware 2D partition: xcd -> (sx, tx); t-panels of 8 tiles for L2 residency
  int id = blockIdx.x;                  // 0..4095
  int xcd = id & 7, within = id >> 3;
  int sx = xcd & 3, tx = xcd >> 2;
  int panel = within >> 7;              // 0..3
  int pl = within & 127;
  int s_tile = sx * 16 + (pl >> 3);     // 0..63
  int t_tile = tx * 32 + panel * 8 + (pl & 7);
  int s0 = s_tile * 16, t0 = t_tile * 16;

  int tid = threadIdx.x;
  int wave = tid >> 6, lane = tid & 63; // wave = b
  int fr = lane & 15;

  const u16* qp = QF + (size_t)(s_tile * 4 + wave) * 16384 + lane * 8;  // 16 heads*2kk*512
  const u16* kp = KF + (size_t)(t_tile * 4 + wave) * 16384 + lane * 8;

  f32x4 acc[16];
  #pragma unroll
  for (int n = 0; n < 16; n++) acc[n] = (f32x4){0.f, 0.f, 0.f, 0.f};

  #pragma unroll
  for (int n = 0; n < 16; n++) {
    #pragma unroll
    for (int kk = 0; kk < 2; kk++) {
      bf16x8 a  = *(const bf16x8*)(qp + (n * 2 + kk) * 512);
      bf16x8 bb = *(const bf16x8*)(kp + (n * 2 + kk) * 512);
      acc[n] = __builtin_amdgcn_mfma_f32_16x16x32_bf16(a, bb, acc[n], 0, 0, 0);
    }
  }

  // stage + store: 2 phases of 8 s-rows through LDS [8][16][4][16] f32 (32KB)
  __shared__ float lds[8192];
  float bv = biasTB[(t0 + (tid >> 4)) * 4 + ((tid >> 2) & 3)];
  int hi = (lane >> 4) & 1;
  int myg = (lane >> 4) >> 1;           // this lane's acc rows live in phase myg

  #pragma unroll
  for (int g = 0; g < 2; g++) {
    __syncthreads();
    if (myg == g) {
      #pragma unroll
      for (int j = 0; j < 4; j++) {
        int lbase = (((hi * 4 + j) * 16 + fr) * 4 + wave) * 64;   // logical byte
        #pragma unroll
        for (int n0 = 0; n0 < 16; n0 += 4) {
          f32x4 v = { acc[n0][j], acc[n0 + 1][j], acc[n0 + 2][j], acc[n0 + 3][j] };
          *(f32x4*)((char*)lds + swzb(lbase + n0 * 4)) = v;
        }
      }
    }
    __syncthreads();
    #pragma unroll
    for (int sr = 0; sr < 8; sr++) {
      f32x4 v = *(const f32x4*)((char*)lds + swzb(sr * 4096 + tid * 16));
      v += bv;
      size_t off = ((size_t)(s0 + g * 8 + sr) * 1024 + t0) * 64 + tid * 4;
      __builtin_nontemporal_store(v, (f32x4*)(out + off));
    }
  }
}

extern "C" void kernel_launch(void* const* d_in, const int* in_sizes, int n_in,
                              void* d_out, int out_size, void* d_ws, size_t ws_size,
                              hipStream_t stream) {
  const float* x   = (const float*)d_in[0];
  const float* r   = (const float*)d_in[1];
  const float* Wq  = (const float*)d_in[2];
  const float* bq  = (const float*)d_in[3];
  const float* Wke = (const float*)d_in[4];
  const float* bke = (const float*)d_in[5];
  const float* Wkr = (const float*)d_in[6];
  const float* bkr = (const float*)d_in[7];
  const float* uu  = (const float*)d_in[8];
  const float* vv  = (const float*)d_in[9];
  float* out = (float*)d_out;
  char* ws = (char*)d_ws;

  u16* A2 = (u16*)(ws + 0);                  // 16 MB  [4096][2048] bf16
  u16* QF = (u16*)(ws + 16777216);           // 8 MB   fragment-major Q
  u16* KF = (u16*)(ws + 25165824);           // 8 MB   fragment-major K
  u16* B2 = (u16*)(ws + 33554432);           // 4 MB   [1024][2048]
  u16* Bq = (u16*)(ws + 37748736);           // 2 MB   [1024][1024]
  float* uwke  = (float*)(ws + 39845888);
  float* vwke  = (float*)(ws + 39849984);
  float* wu    = (float*)(ws + 39854080);
  float* wv    = (float*)(ws + 39858176);
  float* biasK = (float*)(ws + 39862272);
  float* cst   = (float*)(ws + 39866368);
  float* biasTB = (float*)(ws + 39866624);   // 16 KB [1024*4]

  k_prep1<<<512, 256, 0, stream>>>(Wke, bke, uu, Wkr, bkr, vv, uwke, vwke);
  k_prep2<<<65, 256, 0, stream>>>(Wke, Wkr, uwke, vwke, bke, bkr, wu, wv, cst);
  k_convert_xr<<<4096, 256, 0, stream>>>(x, r, A2);
  k_convert_w<<<1024, 256, 0, stream>>>(Wq, Wke, Wkr, bke, bkr, Bq, B2, biasK);
  k_gemm<<<dim3(8, 32, 2), 256, 0, stream>>>(A2, Bq, B2, bq, biasK, QF, KF);
  k_bias<<<1024, 256, 0, stream>>>(x, r, wu, wv, cst, biasTB);
  k_attn<<<4096, 256, 0, stream>>>(QF, KF, biasTB, out);
}